// Round 6
// baseline (242.827 us; speedup 1.0000x reference)
//
#include <hip/hip_runtime.h>
#include <hip/hip_bf16.h>

#define D_MODEL 1024
#define NHEAD   16
#define HDK     64
#define SEQ     2048
#define BATCH   2
#define BS      (BATCH * SEQ)

typedef __attribute__((ext_vector_type(8))) short bf16x8;
typedef __attribute__((ext_vector_type(4))) float f32x4;

__device__ __forceinline__ unsigned short f2bf(float f) {
    unsigned u = __builtin_bit_cast(unsigned, f);
    u += 0x7fffu + ((u >> 16) & 1u);          // round-to-nearest-even
    return (unsigned short)(u >> 16);
}

// pack hi16(x):hi16(y) -> (hi16(y)<<16)|hi16(x) with one v_perm_b32 (truncation)
__device__ __forceinline__ unsigned pack_hi(float x, float y) {
    return __builtin_amdgcn_perm(__builtin_bit_cast(unsigned, y),
                                 __builtin_bit_cast(unsigned, x), 0x07060302u);
}

typedef const void __attribute__((address_space(1))) gas_void;
typedef void __attribute__((address_space(3))) las_void;

__device__ __forceinline__ void gll16(const void* g, void* l) {
    __builtin_amdgcn_global_load_lds((gas_void*)g, (las_void*)l, 16, 0, 0);
}

// ---------------------------------------------------------------------------
// fp32 -> bf16 casts
// ---------------------------------------------------------------------------
__device__ __forceinline__ void cast_body(const float* __restrict__ src,
                                          unsigned short* __restrict__ dst, int i) {
    const float4* p = (const float4*)src + (size_t)i * 2;
    float4 a = p[0], b = p[1];
    ushort4 lo = make_ushort4(f2bf(a.x), f2bf(a.y), f2bf(a.z), f2bf(a.w));
    ushort4 hi = make_ushort4(f2bf(b.x), f2bf(b.y), f2bf(b.z), f2bf(b.w));
    ushort4* q = (ushort4*)dst + (size_t)i * 2;
    q[0] = lo; q[1] = hi;
}

__global__ __launch_bounds__(256)
void cast_act(const float* a, const float* b, const float* c,
              unsigned short* oa, unsigned short* ob, unsigned short* oc, int n8) {
    int i = blockIdx.x * 256 + threadIdx.x;
    if (i >= n8) return;
    const float* s = blockIdx.y == 0 ? a : blockIdx.y == 1 ? b : c;
    unsigned short* d = blockIdx.y == 0 ? oa : blockIdx.y == 1 ? ob : oc;
    cast_body(s, d, i);
}

__global__ __launch_bounds__(256)
void cast_wt(const float* a, const float* b, const float* c, const float* dd,
             unsigned short* oa, unsigned short* ob, unsigned short* oc, unsigned short* od, int n8) {
    int i = blockIdx.x * 256 + threadIdx.x;
    if (i >= n8) return;
    const float* s = blockIdx.y == 0 ? a : blockIdx.y == 1 ? b : blockIdx.y == 2 ? c : dd;
    unsigned short* d = blockIdx.y == 0 ? oa : blockIdx.y == 1 ? ob : blockIdx.y == 2 ? oc : od;
    cast_body(s, d, i);
}

// ---------------------------------------------------------------------------
// GEMM K-loop, BM=128 BN=128 BK=64, 256 thr, wave -> 64x64 quadrant.
// ---------------------------------------------------------------------------
__device__ __forceinline__ void gemm_kloop128(const unsigned short* __restrict__ X,
                                              const unsigned short* __restrict__ W,
                                              unsigned short* As, unsigned short* Bs,
                                              int bm, int bn, f32x4 acc[4][4]) {
    const int t    = threadIdx.x;
    const int w    = t >> 6;
    const int L    = t & 63;
    const int quad = L >> 4;
    const int lm   = L & 15;
    const int r8   = L >> 3;
    const int sl   = L & 7;
    const int xcol = ((sl ^ r8) & 7) * 8;
    const int wr   = (w >> 1) * 64;
    const int wc   = (w & 1) * 64;

    for (int kt = 0; kt < D_MODEL; kt += 64) {
        __syncthreads();
        #pragma unroll
        for (int i = 0; i < 4; ++i) {
            int c = w * 4 + i;
            gll16(X + (size_t)(bm + c * 8 + r8) * D_MODEL + kt + xcol, &As[c * 512]);
        }
        #pragma unroll
        for (int i = 0; i < 4; ++i) {
            int c = w * 4 + i;
            gll16(W + (size_t)(bn + c * 8 + r8) * D_MODEL + kt + xcol, &Bs[c * 512]);
        }
        __syncthreads();

        #pragma unroll
        for (int ch = 0; ch < 2; ++ch) {
            bf16x8 af[4], bfr[4];
            #pragma unroll
            for (int ms = 0; ms < 4; ++ms) {
                int row = wr + ms * 16 + lm;
                af[ms] = *(const bf16x8*)&As[row * 64 + (((ch * 4 + quad) ^ (row & 7)) * 8)];
            }
            #pragma unroll
            for (int ns = 0; ns < 4; ++ns) {
                int row = wc + ns * 16 + lm;
                bfr[ns] = *(const bf16x8*)&Bs[row * 64 + (((ch * 4 + quad) ^ (row & 7)) * 8)];
            }
            #pragma unroll
            for (int ms = 0; ms < 4; ++ms)
                #pragma unroll
                for (int ns = 0; ns < 4; ++ns)
                    acc[ms][ns] = __builtin_amdgcn_mfma_f32_16x16x32_bf16(
                        af[ms], bfr[ns], acc[ms][ns], 0, 0, 0);
        }
    }
}

// BM=128 BN=64 variant
__device__ __forceinline__ void gemm_kloop64(const unsigned short* __restrict__ X,
                                             const unsigned short* __restrict__ W,
                                             unsigned short* As, unsigned short* Bs,
                                             int bm, int bn, f32x4 acc[2][4]) {
    const int t    = threadIdx.x;
    const int w    = t >> 6;
    const int L    = t & 63;
    const int quad = L >> 4;
    const int lm   = L & 15;
    const int r8   = L >> 3;
    const int sl   = L & 7;
    const int xcol = ((sl ^ r8) & 7) * 8;

    for (int kt = 0; kt < D_MODEL; kt += 64) {
        __syncthreads();
        #pragma unroll
        for (int i = 0; i < 4; ++i) {
            int c = w * 4 + i;
            gll16(X + (size_t)(bm + c * 8 + r8) * D_MODEL + kt + xcol, &As[c * 512]);
        }
        #pragma unroll
        for (int i = 0; i < 2; ++i) {
            int c = w * 2 + i;
            gll16(W + (size_t)(bn + c * 8 + r8) * D_MODEL + kt + xcol, &Bs[c * 512]);
        }
        __syncthreads();

        #pragma unroll
        for (int ch = 0; ch < 2; ++ch) {
            bf16x8 af[2], bfr[4];
            #pragma unroll
            for (int ms = 0; ms < 2; ++ms) {
                int row = w * 32 + ms * 16 + lm;
                af[ms] = *(const bf16x8*)&As[row * 64 + (((ch * 4 + quad) ^ (row & 7)) * 8)];
            }
            #pragma unroll
            for (int ns = 0; ns < 4; ++ns) {
                int row = ns * 16 + lm;
                bfr[ns] = *(const bf16x8*)&Bs[row * 64 + (((ch * 4 + quad) ^ (row & 7)) * 8)];
            }
            #pragma unroll
            for (int ms = 0; ms < 2; ++ms)
                #pragma unroll
                for (int ns = 0; ns < 4; ++ns)
                    acc[ms][ns] = __builtin_amdgcn_mfma_f32_16x16x32_bf16(
                        af[ms], bfr[ns], acc[ms][ns], 0, 0, 0);
        }
    }
}

// ---------------------------------------------------------------------------
// Fused Q/K/V projections. z=0: Q (x0.125, row-major), z=1: K (row-major),
// z=2: V transposed per head: VT[(b*16+h)*64+d][s].
// ---------------------------------------------------------------------------
__global__ __launch_bounds__(256, 3)
void proj_gemm(const unsigned short* __restrict__ qx, const unsigned short* __restrict__ kx,
               const unsigned short* __restrict__ vx, const unsigned short* __restrict__ wq,
               const unsigned short* __restrict__ wk, const unsigned short* __restrict__ wv,
               unsigned short* __restrict__ Qp, unsigned short* __restrict__ Kp,
               unsigned short* __restrict__ VT) {
    __shared__ __align__(16) unsigned short As[128 * 64];
    __shared__ __align__(16) unsigned short Bs[128 * 64];

    const int p = blockIdx.z;
    const unsigned short* X = p == 0 ? qx : p == 1 ? kx : vx;
    const unsigned short* W = p == 0 ? wq : p == 1 ? wk : wv;
    const int bm = blockIdx.y * 128, bn = blockIdx.x * 128;

    f32x4 acc[4][4];
    #pragma unroll
    for (int ms = 0; ms < 4; ++ms)
        #pragma unroll
        for (int ns = 0; ns < 4; ++ns)
            acc[ms][ns] = (f32x4){0.f, 0.f, 0.f, 0.f};

    gemm_kloop128(X, W, As, Bs, bm, bn, acc);

    const int t = threadIdx.x, w = t >> 6, L = t & 63, quad = L >> 4, lm = L & 15;
    const int wr = (w >> 1) * 64, wc = (w & 1) * 64;
    if (p == 2) {
        const int b    = bm >> 11;
        const int s_in = (bm & (SEQ - 1)) + wr;
        #pragma unroll
        for (int ms = 0; ms < 4; ++ms)
            #pragma unroll
            for (int ns = 0; ns < 4; ++ns) {
                int dg = bn + wc + ns * 16 + lm;
                int h  = dg >> 6, d = dg & 63;
                ushort4 pk = make_ushort4(f2bf(acc[ms][ns][0]), f2bf(acc[ms][ns][1]),
                                          f2bf(acc[ms][ns][2]), f2bf(acc[ms][ns][3]));
                *(ushort4*)&VT[((size_t)((b * NHEAD + h) * HDK + d)) * SEQ +
                               s_in + ms * 16 + quad * 4] = pk;
            }
    } else {
        unsigned short* Y = p == 0 ? Qp : Kp;
        const float scl = p == 0 ? 0.125f : 1.0f;
        #pragma unroll
        for (int ms = 0; ms < 4; ++ms)
            #pragma unroll
            for (int ns = 0; ns < 4; ++ns)
                #pragma unroll
                for (int r = 0; r < 4; ++r)
                    Y[(size_t)(bm + wr + ms * 16 + quad * 4 + r) * D_MODEL +
                      bn + wc + ns * 16 + lm] = f2bf(acc[ms][ns][r] * scl);
    }
}

__global__ __launch_bounds__(256)
void out_gemm(const unsigned short* __restrict__ X, const unsigned short* __restrict__ W,
              float* __restrict__ Y) {
    __shared__ __align__(16) unsigned short As[128 * 64];
    __shared__ __align__(16) unsigned short Bs[64 * 64];
    const int bm = blockIdx.y * 128, bn = blockIdx.x * 64;

    f32x4 acc[2][4];
    #pragma unroll
    for (int ms = 0; ms < 2; ++ms)
        #pragma unroll
        for (int ns = 0; ns < 4; ++ns)
            acc[ms][ns] = (f32x4){0.f, 0.f, 0.f, 0.f};

    gemm_kloop64(X, W, As, Bs, bm, bn, acc);

    const int t = threadIdx.x, w = t >> 6, L = t & 63, quad = L >> 4, lm = L & 15;
    #pragma unroll
    for (int ms = 0; ms < 2; ++ms)
        #pragma unroll
        for (int ns = 0; ns < 4; ++ns)
            #pragma unroll
            for (int r = 0; r < 4; ++r)
                Y[(size_t)(bm + w * 32 + ms * 16 + quad * 4 + r) * D_MODEL +
                  bn + ns * 16 + lm] = acc[ms][ns][r];
}

// ---------------------------------------------------------------------------
// Flash attention, causal, S^T form. 128 thr = 2 waves x 32 q-rows (2 strips
// of 16). 1-D grid of 512 blocks; flat id remapped so all 16 pair-blocks of
// one (b,h) land on one XCD (flat%8 heuristic) -> K/V L2-resident (2 MB/XCD).
// Block handles qt = pidx then 31-pidx (33 kv-tiles, perfectly balanced).
// All staging (Q,K,V) via global_load_lds into XOR-swizzled LDS, K/V
// double-buffered -> one barrier per tile. K/V fragments hoisted (strip-
// invariant): each tile read once per wave.
// ---------------------------------------------------------------------------
__global__ __launch_bounds__(128)
void attn_mfma(const unsigned short* __restrict__ Q, const unsigned short* __restrict__ K,
               const unsigned short* __restrict__ VT, unsigned short* __restrict__ A) {
    __shared__ __align__(16) unsigned short Ks[2][64 * 64];
    __shared__ __align__(16) unsigned short Vs[2][64 * 64];
    __shared__ __align__(16) unsigned short Qs[64 * 64];
    __shared__ __align__(16) unsigned short Ps[2][16 * 68];

    const int t    = threadIdx.x;
    const int w    = t >> 6;
    const int L    = t & 63;
    const int quad = L >> 4;
    const int lm   = L & 15;
    const int r8   = L >> 3;
    const int xcol = ((L & 7) ^ r8) * 8;       // swizzled global 16B-slot

    // block remap: f%8 selects XCD-group; 16 pair-blocks of one bh share it
    const int f    = blockIdx.x;
    const int g    = (f & 7) + ((f >> 7) << 3);    // bh index 0..31
    const int pidx = (f >> 3) & 15;                // pair index 0..15
    const int b    = g >> 4, h = g & 15;
    const size_t hb  = (size_t)b * SEQ * D_MODEL + h * HDK;
    const size_t vhb = (size_t)(b * NHEAD + h) * HDK;

    unsigned short* ps = &Ps[w][0];

    for (int half = 0; half < 2; ++half) {
        const int qt = half ? 31 - pidx : pidx;
        const int q0 = qt * 64;

        // prologue: stage Q tile + K/V tile 0 (async)
        #pragma unroll
        for (int i = 0; i < 4; ++i) {
            int c = w * 4 + i;
            gll16(Q + hb + (size_t)(q0 + c * 8 + r8) * D_MODEL + xcol, &Qs[c * 512]);
            gll16(K + hb + (size_t)(c * 8 + r8) * D_MODEL + xcol, &Ks[0][c * 512]);
            gll16(VT + (vhb + c * 8 + r8) * SEQ + xcol, &Vs[0][c * 512]);
        }
        __syncthreads();

        // Q fragments (B-operand), 2 strips x 2 d-halves
        bf16x8 Qf[2][2];
        #pragma unroll
        for (int s = 0; s < 2; ++s) {
            int row = w * 32 + s * 16 + lm;
            Qf[s][0] = *(const bf16x8*)&Qs[row * 64 + ((quad ^ (row & 7)) * 8)];
            Qf[s][1] = *(const bf16x8*)&Qs[row * 64 + (((4 + quad) ^ (row & 7)) * 8)];
        }

        f32x4 Oacc[2][4];
        #pragma unroll
        for (int s = 0; s < 2; ++s)
            #pragma unroll
            for (int nt = 0; nt < 4; ++nt)
                Oacc[s][nt] = (f32x4){0.f, 0.f, 0.f, 0.f};
        float m_run[2] = {-INFINITY, -INFINITY};
        float l_run[2] = {0.f, 0.f};

        int bb = 0;
        for (int kt = 0; kt <= qt; ++kt) {
            if (kt < qt) {                      // async-stage tile kt+1
                #pragma unroll
                for (int i = 0; i < 4; ++i) {
                    int c = w * 4 + i;
                    gll16(K + hb + (size_t)((kt + 1) * 64 + c * 8 + r8) * D_MODEL + xcol,
                          &Ks[bb ^ 1][c * 512]);
                    gll16(VT + (vhb + c * 8 + r8) * SEQ + (kt + 1) * 64 + xcol,
                          &Vs[bb ^ 1][c * 512]);
                }
            }
            const unsigned short* Kc = Ks[bb];
            const unsigned short* Vc = Vs[bb];

            // hoisted K/V fragments (strip-invariant): one LDS read per tile
            bf16x8 Kf[4][2], Vf[4][2];
            #pragma unroll
            for (int ct = 0; ct < 4; ++ct) {
                int row = ct * 16 + lm;
                int o0  = row * 64 + ((quad ^ (row & 7)) * 8);
                int o1  = row * 64 + (((4 + quad) ^ (row & 7)) * 8);
                Kf[ct][0] = *(const bf16x8*)&Kc[o0];
                Kf[ct][1] = *(const bf16x8*)&Kc[o1];
                Vf[ct][0] = *(const bf16x8*)&Vc[o0];
                Vf[ct][1] = *(const bf16x8*)&Vc[o1];
            }

            #pragma unroll
            for (int s = 0; s < 2; ++s) {
                const int qrow = q0 + w * 32 + s * 16 + lm;
                f32x4 S[4];
                #pragma unroll
                for (int ct = 0; ct < 4; ++ct) {
                    f32x4 z = (f32x4){0.f, 0.f, 0.f, 0.f};
                    z = __builtin_amdgcn_mfma_f32_16x16x32_bf16(Kf[ct][0], Qf[s][0], z, 0, 0, 0);
                    z = __builtin_amdgcn_mfma_f32_16x16x32_bf16(Kf[ct][1], Qf[s][1], z, 0, 0, 0);
                    S[ct] = z;
                }

                if (kt == qt) {                 // causal mask (diag tile only)
                    #pragma unroll
                    for (int ct = 0; ct < 4; ++ct)
                        #pragma unroll
                        for (int r = 0; r < 4; ++r)
                            if ((q0 + ct * 16 + quad * 4 + r) > qrow)
                                S[ct][r] = -1e30f;
                }

                // online softmax (scalar per-lane state, 2 shuffles)
                float m = fmaxf(fmaxf(fmaxf(S[0][0], S[0][1]), fmaxf(S[0][2], S[0][3])),
                                fmaxf(fmaxf(S[1][0], S[1][1]), fmaxf(S[1][2], S[1][3])));
                m = fmaxf(m, fmaxf(fmaxf(fmaxf(S[2][0], S[2][1]), fmaxf(S[2][2], S[2][3])),
                                   fmaxf(fmaxf(S[3][0], S[3][1]), fmaxf(S[3][2], S[3][3]))));
                m = fmaxf(m, __shfl_xor(m, 16));
                m = fmaxf(m, __shfl_xor(m, 32));
                const float m_new = fmaxf(m_run[s], m);
                const float alpha = __expf(m_run[s] - m_new);
                m_run[s] = m_new;
                float psum = 0.f;
                #pragma unroll
                for (int ct = 0; ct < 4; ++ct)
                    #pragma unroll
                    for (int r = 0; r < 4; ++r) {
                        float e = __expf(S[ct][r] - m_new);
                        S[ct][r] = e;
                        psum += e;
                    }
                psum += __shfl_xor(psum, 16);
                psum += __shfl_xor(psum, 32);
                l_run[s] = l_run[s] * alpha + psum;

                // P^T -> wave-private slab (truncation pack), then B-frags
                #pragma unroll
                for (int ct = 0; ct < 4; ++ct) {
                    uint2 pw = make_uint2(pack_hi(S[ct][0], S[ct][1]),
                                          pack_hi(S[ct][2], S[ct][3]));
                    *(uint2*)&ps[lm * 68 + ct * 16 + quad * 4] = pw;
                }
                bf16x8 Pb0 = *(const bf16x8*)&ps[lm * 68 + quad * 8];
                bf16x8 Pb1 = *(const bf16x8*)&ps[lm * 68 + 32 + quad * 8];

                // O^T = O^T*alpha + V^T P^T
                #pragma unroll
                for (int nt = 0; nt < 4; ++nt) {
                    f32x4 o = Oacc[s][nt];
                    #pragma unroll
                    for (int r = 0; r < 4; ++r) o[r] *= alpha;
                    o = __builtin_amdgcn_mfma_f32_16x16x32_bf16(Vf[nt][0], Pb0, o, 0, 0, 0);
                    o = __builtin_amdgcn_mfma_f32_16x16x32_bf16(Vf[nt][1], Pb1, o, 0, 0, 0);
                    Oacc[s][nt] = o;
                }
            }

            __syncthreads();                   // one barrier per tile
            bb ^= 1;
        }

        // epilogue: O^T/l -> slab [q][d] -> coalesced stores (per strip)
        #pragma unroll
        for (int s = 0; s < 2; ++s) {
            const float inv_l = 1.f / l_run[s];
            #pragma unroll
            for (int nt = 0; nt < 4; ++nt) {
                ushort4 pk = make_ushort4(f2bf(Oacc[s][nt][0] * inv_l),
                                          f2bf(Oacc[s][nt][1] * inv_l),
                                          f2bf(Oacc[s][nt][2] * inv_l),
                                          f2bf(Oacc[s][nt][3] * inv_l));
                *(ushort4*)&ps[lm * 68 + nt * 16 + quad * 4] = pk;
            }
            #pragma unroll
            for (int cc = 0; cc < 2; ++cc) {
                int chunk = cc * 64 + L;
                int row = chunk >> 3, seg = chunk & 7;
                uint4 val = *(const uint4*)&ps[row * 68 + seg * 8];
                *(uint4*)&A[hb + (size_t)(q0 + w * 32 + s * 16 + row) * D_MODEL + seg * 8] = val;
            }
        }
    }
}

// ---------------------------------------------------------------------------
extern "C" void kernel_launch(void* const* d_in, const int* in_sizes, int n_in,
                              void* d_out, int out_size, void* d_ws, size_t ws_size,
                              hipStream_t stream) {
    const float* q  = (const float*)d_in[0];
    const float* k  = (const float*)d_in[1];
    const float* v  = (const float*)d_in[2];
    const float* Wq = (const float*)d_in[4];
    const float* Wk = (const float*)d_in[5];
    const float* Wv = (const float*)d_in[6];
    const float* Wo = (const float*)d_in[7];
    float* out = (float*)d_out;

    char* ws = (char*)d_ws;
    const size_t MB = 1024 * 1024;
    unsigned short* qb  = (unsigned short*)(ws + 0 * MB);
    unsigned short* kb  = (unsigned short*)(ws + 8 * MB);
    unsigned short* vb  = (unsigned short*)(ws + 16 * MB);
    unsigned short* wqb = (unsigned short*)(ws + 24 * MB);
    unsigned short* wkb = (unsigned short*)(ws + 26 * MB);
    unsigned short* wvb = (unsigned short*)(ws + 28 * MB);
    unsigned short* wob = (unsigned short*)(ws + 30 * MB);
    unsigned short* Qp  = (unsigned short*)(ws + 32 * MB);
    unsigned short* Kp  = (unsigned short*)(ws + 40 * MB);
    unsigned short* VTp = (unsigned short*)(ws + 48 * MB);
    unsigned short* Ap  = (unsigned short*)(ws + 56 * MB);

    const int nX8 = BS * D_MODEL / 8;
    const int nW8 = D_MODEL * D_MODEL / 8;
    cast_act<<<dim3(nX8 / 256, 3), 256, 0, stream>>>(q, k, v, qb, kb, vb, nX8);
    cast_wt <<<dim3(nW8 / 256, 4), 256, 0, stream>>>(Wq, Wk, Wv, Wo, wqb, wkb, wvb, wob, nW8);

    proj_gemm<<<dim3(D_MODEL / 128, BS / 128, 3), 256, 0, stream>>>(
        qb, kb, vb, wqb, wkb, wvb, Qp, Kp, VTp);

    attn_mfma<<<dim3(512), 128, 0, stream>>>(Qp, Kp, VTp, Ap);

    out_gemm<<<dim3(D_MODEL / 64, BS / 128), 256, 0, stream>>>(Ap, wob, out);
}

// Round 7
// 236.301 us; speedup vs baseline: 1.0276x; 1.0276x over previous
//
#include <hip/hip_runtime.h>
#include <hip/hip_bf16.h>

#define D_MODEL 1024
#define NHEAD   16
#define HDK     64
#define SEQ     2048
#define BATCH   2
#define BS      (BATCH * SEQ)

typedef __attribute__((ext_vector_type(8))) short bf16x8;
typedef __attribute__((ext_vector_type(4))) float f32x4;

__device__ __forceinline__ unsigned short f2bf(float f) {
    unsigned u = __builtin_bit_cast(unsigned, f);
    u += 0x7fffu + ((u >> 16) & 1u);          // round-to-nearest-even
    return (unsigned short)(u >> 16);
}

// pack hi16(x):hi16(y) with one v_perm_b32 (truncation; P in [0,1])
__device__ __forceinline__ unsigned pack_hi(float x, float y) {
    return __builtin_amdgcn_perm(__builtin_bit_cast(unsigned, y),
                                 __builtin_bit_cast(unsigned, x), 0x07060302u);
}

__device__ __forceinline__ float fexp2(float x) {
#if __has_builtin(__builtin_amdgcn_exp2f)
    return __builtin_amdgcn_exp2f(x);
#else
    return exp2f(x);
#endif
}

typedef const void __attribute__((address_space(1))) gas_void;
typedef void __attribute__((address_space(3))) las_void;

__device__ __forceinline__ void gll16(const void* g, void* l) {
    __builtin_amdgcn_global_load_lds((gas_void*)g, (las_void*)l, 16, 0, 0);
}

// ---------------------------------------------------------------------------
// fp32 -> bf16 cast, all 7 tensors in one launch (y = tensor index)
// ---------------------------------------------------------------------------
__global__ __launch_bounds__(256)
void cast_all(const float* q, const float* k, const float* v,
              const float* wq, const float* wk, const float* wv, const float* wo,
              unsigned short* oq, unsigned short* ok, unsigned short* ov,
              unsigned short* owq, unsigned short* owk, unsigned short* owv,
              unsigned short* owo, int nact8, int nwt8) {
    const int y = blockIdx.y;
    const int n8 = y < 3 ? nact8 : nwt8;
    int i = blockIdx.x * 256 + threadIdx.x;
    if (i >= n8) return;
    const float* s; unsigned short* d;
    switch (y) {
        case 0: s = q;  d = oq;  break;
        case 1: s = k;  d = ok;  break;
        case 2: s = v;  d = ov;  break;
        case 3: s = wq; d = owq; break;
        case 4: s = wk; d = owk; break;
        case 5: s = wv; d = owv; break;
        default: s = wo; d = owo; break;
    }
    const float4* p = (const float4*)s + (size_t)i * 2;
    float4 a = p[0], b = p[1];
    ushort4 lo = make_ushort4(f2bf(a.x), f2bf(a.y), f2bf(a.z), f2bf(a.w));
    ushort4 hi = make_ushort4(f2bf(b.x), f2bf(b.y), f2bf(b.z), f2bf(b.w));
    ushort4* o = (ushort4*)d + (size_t)i * 2;
    o[0] = lo; o[1] = hi;
}

// ---------------------------------------------------------------------------
// GEMM K-loop, BM=128 BN=128 BK=64, 256 thr, wave -> 64x64 quadrant.
// gll16 staging into XOR-swizzled unpadded LDS.
// ---------------------------------------------------------------------------
__device__ __forceinline__ void gemm_kloop128(const unsigned short* __restrict__ X,
                                              const unsigned short* __restrict__ W,
                                              unsigned short* As, unsigned short* Bs,
                                              int bm, int bn, f32x4 acc[4][4]) {
    const int t    = threadIdx.x;
    const int w    = t >> 6;
    const int L    = t & 63;
    const int quad = L >> 4;
    const int lm   = L & 15;
    const int r8   = L >> 3;
    const int sl   = L & 7;
    const int xcol = ((sl ^ r8) & 7) * 8;
    const int wr   = (w >> 1) * 64;
    const int wc   = (w & 1) * 64;

    for (int kt = 0; kt < D_MODEL; kt += 64) {
        __syncthreads();
        #pragma unroll
        for (int i = 0; i < 4; ++i) {
            int c = w * 4 + i;
            gll16(X + (size_t)(bm + c * 8 + r8) * D_MODEL + kt + xcol, &As[c * 512]);
        }
        #pragma unroll
        for (int i = 0; i < 4; ++i) {
            int c = w * 4 + i;
            gll16(W + (size_t)(bn + c * 8 + r8) * D_MODEL + kt + xcol, &Bs[c * 512]);
        }
        __syncthreads();

        #pragma unroll
        for (int ch = 0; ch < 2; ++ch) {
            bf16x8 af[4], bfr[4];
            #pragma unroll
            for (int ms = 0; ms < 4; ++ms) {
                int row = wr + ms * 16 + lm;
                af[ms] = *(const bf16x8*)&As[row * 64 + (((ch * 4 + quad) ^ (row & 7)) * 8)];
            }
            #pragma unroll
            for (int ns = 0; ns < 4; ++ns) {
                int row = wc + ns * 16 + lm;
                bfr[ns] = *(const bf16x8*)&Bs[row * 64 + (((ch * 4 + quad) ^ (row & 7)) * 8)];
            }
            #pragma unroll
            for (int ms = 0; ms < 4; ++ms)
                #pragma unroll
                for (int ns = 0; ns < 4; ++ns)
                    acc[ms][ns] = __builtin_amdgcn_mfma_f32_16x16x32_bf16(
                        af[ms], bfr[ns], acc[ms][ns], 0, 0, 0);
        }
    }
}

// BM=128 BN=64 variant
__device__ __forceinline__ void gemm_kloop64(const unsigned short* __restrict__ X,
                                             const unsigned short* __restrict__ W,
                                             unsigned short* As, unsigned short* Bs,
                                             int bm, int bn, f32x4 acc[2][4]) {
    const int t    = threadIdx.x;
    const int w    = t >> 6;
    const int L    = t & 63;
    const int quad = L >> 4;
    const int lm   = L & 15;
    const int r8   = L >> 3;
    const int sl   = L & 7;
    const int xcol = ((sl ^ r8) & 7) * 8;

    for (int kt = 0; kt < D_MODEL; kt += 64) {
        __syncthreads();
        #pragma unroll
        for (int i = 0; i < 4; ++i) {
            int c = w * 4 + i;
            gll16(X + (size_t)(bm + c * 8 + r8) * D_MODEL + kt + xcol, &As[c * 512]);
        }
        #pragma unroll
        for (int i = 0; i < 2; ++i) {
            int c = w * 2 + i;
            gll16(W + (size_t)(bn + c * 8 + r8) * D_MODEL + kt + xcol, &Bs[c * 512]);
        }
        __syncthreads();

        #pragma unroll
        for (int ch = 0; ch < 2; ++ch) {
            bf16x8 af[2], bfr[4];
            #pragma unroll
            for (int ms = 0; ms < 2; ++ms) {
                int row = w * 32 + ms * 16 + lm;
                af[ms] = *(const bf16x8*)&As[row * 64 + (((ch * 4 + quad) ^ (row & 7)) * 8)];
            }
            #pragma unroll
            for (int ns = 0; ns < 4; ++ns) {
                int row = ns * 16 + lm;
                bfr[ns] = *(const bf16x8*)&Bs[row * 64 + (((ch * 4 + quad) ^ (row & 7)) * 8)];
            }
            #pragma unroll
            for (int ms = 0; ms < 2; ++ms)
                #pragma unroll
                for (int ns = 0; ns < 4; ++ns)
                    acc[ms][ns] = __builtin_amdgcn_mfma_f32_16x16x32_bf16(
                        af[ms], bfr[ns], acc[ms][ns], 0, 0, 0);
        }
    }
}

// ---------------------------------------------------------------------------
// Fused Q/K/V projections. z=0: Q (x 0.125*log2e -> exp2-domain softmax,
// row-major), z=1: K (row-major), z=2: V transposed: VT[(b*16+h)*64+d][s].
// ---------------------------------------------------------------------------
__global__ __launch_bounds__(256, 3)
void proj_gemm(const unsigned short* __restrict__ qx, const unsigned short* __restrict__ kx,
               const unsigned short* __restrict__ vx, const unsigned short* __restrict__ wq,
               const unsigned short* __restrict__ wk, const unsigned short* __restrict__ wv,
               unsigned short* __restrict__ Qp, unsigned short* __restrict__ Kp,
               unsigned short* __restrict__ VT) {
    __shared__ __align__(16) unsigned short As[128 * 64];
    __shared__ __align__(16) unsigned short Bs[128 * 64];

    const int p = blockIdx.z;
    const unsigned short* X = p == 0 ? qx : p == 1 ? kx : vx;
    const unsigned short* W = p == 0 ? wq : p == 1 ? wk : wv;
    const int bm = blockIdx.y * 128, bn = blockIdx.x * 128;

    f32x4 acc[4][4];
    #pragma unroll
    for (int ms = 0; ms < 4; ++ms)
        #pragma unroll
        for (int ns = 0; ns < 4; ++ns)
            acc[ms][ns] = (f32x4){0.f, 0.f, 0.f, 0.f};

    gemm_kloop128(X, W, As, Bs, bm, bn, acc);

    const int t = threadIdx.x, w = t >> 6, L = t & 63, quad = L >> 4, lm = L & 15;
    const int wr = (w >> 1) * 64, wc = (w & 1) * 64;
    if (p == 2) {
        const int b    = bm >> 11;
        const int s_in = (bm & (SEQ - 1)) + wr;
        #pragma unroll
        for (int ms = 0; ms < 4; ++ms)
            #pragma unroll
            for (int ns = 0; ns < 4; ++ns) {
                int dg = bn + wc + ns * 16 + lm;
                int h  = dg >> 6, d = dg & 63;
                ushort4 pk = make_ushort4(f2bf(acc[ms][ns][0]), f2bf(acc[ms][ns][1]),
                                          f2bf(acc[ms][ns][2]), f2bf(acc[ms][ns][3]));
                *(ushort4*)&VT[((size_t)((b * NHEAD + h) * HDK + d)) * SEQ +
                               s_in + ms * 16 + quad * 4] = pk;
            }
    } else {
        unsigned short* Y = p == 0 ? Qp : Kp;
        // Q scale = 1/sqrt(64) * log2(e)  (softmax done in exp2 domain)
        const float scl = p == 0 ? 0.18033688011112042f : 1.0f;
        #pragma unroll
        for (int ms = 0; ms < 4; ++ms)
            #pragma unroll
            for (int ns = 0; ns < 4; ++ns)
                #pragma unroll
                for (int r = 0; r < 4; ++r)
                    Y[(size_t)(bm + wr + ms * 16 + quad * 4 + r) * D_MODEL +
                      bn + wc + ns * 16 + lm] = f2bf(acc[ms][ns][r] * scl);
    }
}

__global__ __launch_bounds__(256)
void out_gemm(const unsigned short* __restrict__ X, const unsigned short* __restrict__ W,
              float* __restrict__ Y) {
    __shared__ __align__(16) unsigned short As[128 * 64];
    __shared__ __align__(16) unsigned short Bs[64 * 64];
    const int bm = blockIdx.y * 128, bn = blockIdx.x * 64;

    f32x4 acc[2][4];
    #pragma unroll
    for (int ms = 0; ms < 2; ++ms)
        #pragma unroll
        for (int ns = 0; ns < 4; ++ns)
            acc[ms][ns] = (f32x4){0.f, 0.f, 0.f, 0.f};

    gemm_kloop64(X, W, As, Bs, bm, bn, acc);

    const int t = threadIdx.x, w = t >> 6, L = t & 63, quad = L >> 4, lm = L & 15;
    #pragma unroll
    for (int ms = 0; ms < 2; ++ms)
        #pragma unroll
        for (int ns = 0; ns < 4; ++ns)
            #pragma unroll
            for (int r = 0; r < 4; ++r)
                Y[(size_t)(bm + w * 32 + ms * 16 + quad * 4 + r) * D_MODEL +
                  bn + ns * 16 + lm] = acc[ms][ns][r];
}

// ---------------------------------------------------------------------------
// Flash attention, causal, S^T form, exp2-domain softmax.
// 1024 blocks x 128 thr (2 waves x 32 q-rows in 2 strips of 16).
// Block f: qt = 31-(f>>5) (longest first), bh = f&31 -> f%8 = bh%8 keeps all
// 32 blocks of one (b,h) on one XCD (K/V L2-resident, 2 MB/XCD).
// K/V staged via gll16 into XOR-swizzled LDS, double-buffered, one barrier
// per tile. K/V fragments hoisted (strip-invariant). Q frags direct global.
// ---------------------------------------------------------------------------
__global__ __launch_bounds__(128)
void attn_mfma(const unsigned short* __restrict__ Q, const unsigned short* __restrict__ K,
               const unsigned short* __restrict__ VT, unsigned short* __restrict__ A) {
    __shared__ __align__(16) unsigned short Ks[2][64 * 64];
    __shared__ __align__(16) unsigned short Vs[2][64 * 64];
    __shared__ __align__(16) unsigned short Ps[2][16 * 68];

    const int t    = threadIdx.x;
    const int w    = t >> 6;
    const int L    = t & 63;
    const int quad = L >> 4;
    const int lm   = L & 15;
    const int r8   = L >> 3;
    const int xcol = ((L & 7) ^ r8) * 8;       // swizzled global 16B-slot

    const int f    = blockIdx.x;
    const int qt   = 31 - (f >> 5);            // longest-qt dispatched first
    const int bh   = f & 31;                   // f%8 == bh%8 -> XCD co-location
    const int b    = bh >> 4, h = bh & 15;
    const int q0   = qt * 64;
    const size_t hb  = (size_t)b * SEQ * D_MODEL + h * HDK;
    const size_t vhb = (size_t)(b * NHEAD + h) * HDK;

    unsigned short* ps = &Ps[w][0];

    // Q fragments (B-operand), direct from global, 2 strips x 2 d-halves
    bf16x8 Qf[2][2];
    #pragma unroll
    for (int s = 0; s < 2; ++s) {
        const unsigned short* qp =
            Q + hb + (size_t)(q0 + w * 32 + s * 16 + lm) * D_MODEL + quad * 8;
        Qf[s][0] = *(const bf16x8*)qp;
        Qf[s][1] = *(const bf16x8*)(qp + 32);
    }

    f32x4 Oacc[2][4];
    #pragma unroll
    for (int s = 0; s < 2; ++s)
        #pragma unroll
        for (int nt = 0; nt < 4; ++nt)
            Oacc[s][nt] = (f32x4){0.f, 0.f, 0.f, 0.f};
    float m_run[2] = {-INFINITY, -INFINITY};
    float l_run[2] = {0.f, 0.f};

    // prologue: stage K/V tile 0 (async)
    #pragma unroll
    for (int i = 0; i < 4; ++i) {
        int c = w * 4 + i;
        gll16(K + hb + (size_t)(c * 8 + r8) * D_MODEL + xcol, &Ks[0][c * 512]);
        gll16(VT + (vhb + c * 8 + r8) * SEQ + xcol, &Vs[0][c * 512]);
    }
    __syncthreads();

    int bb = 0;
    for (int kt = 0; kt <= qt; ++kt) {
        if (kt < qt) {                          // async-stage tile kt+1
            #pragma unroll
            for (int i = 0; i < 4; ++i) {
                int c = w * 4 + i;
                gll16(K + hb + (size_t)((kt + 1) * 64 + c * 8 + r8) * D_MODEL + xcol,
                      &Ks[bb ^ 1][c * 512]);
                gll16(VT + (vhb + c * 8 + r8) * SEQ + (kt + 1) * 64 + xcol,
                      &Vs[bb ^ 1][c * 512]);
            }
        }
        const unsigned short* Kc = Ks[bb];
        const unsigned short* Vc = Vs[bb];

        // hoisted K/V fragments (strip-invariant): one LDS read per tile
        bf16x8 Kf[4][2], Vf[4][2];
        #pragma unroll
        for (int ct = 0; ct < 4; ++ct) {
            int row = ct * 16 + lm;
            int o0  = row * 64 + ((quad ^ (row & 7)) * 8);
            int o1  = row * 64 + (((4 + quad) ^ (row & 7)) * 8);
            Kf[ct][0] = *(const bf16x8*)&Kc[o0];
            Kf[ct][1] = *(const bf16x8*)&Kc[o1];
            Vf[ct][0] = *(const bf16x8*)&Vc[o0];
            Vf[ct][1] = *(const bf16x8*)&Vc[o1];
        }

        #pragma unroll
        for (int s = 0; s < 2; ++s) {
            const int qrow = q0 + w * 32 + s * 16 + lm;
            f32x4 S[4];
            #pragma unroll
            for (int ct = 0; ct < 4; ++ct) {
                f32x4 z = (f32x4){0.f, 0.f, 0.f, 0.f};
                z = __builtin_amdgcn_mfma_f32_16x16x32_bf16(Kf[ct][0], Qf[s][0], z, 0, 0, 0);
                z = __builtin_amdgcn_mfma_f32_16x16x32_bf16(Kf[ct][1], Qf[s][1], z, 0, 0, 0);
                S[ct] = z;
            }

            if (kt == qt) {                     // causal mask (diag tile only)
                #pragma unroll
                for (int ct = 0; ct < 4; ++ct)
                    #pragma unroll
                    for (int r = 0; r < 4; ++r)
                        if ((q0 + ct * 16 + quad * 4 + r) > qrow)
                            S[ct][r] = -1e30f;
            }

            // online softmax, exp2 domain (scores pre-scaled by log2e/8)
            float m = fmaxf(fmaxf(fmaxf(S[0][0], S[0][1]), fmaxf(S[0][2], S[0][3])),
                            fmaxf(fmaxf(S[1][0], S[1][1]), fmaxf(S[1][2], S[1][3])));
            m = fmaxf(m, fmaxf(fmaxf(fmaxf(S[2][0], S[2][1]), fmaxf(S[2][2], S[2][3])),
                               fmaxf(fmaxf(S[3][0], S[3][1]), fmaxf(S[3][2], S[3][3]))));
            m = fmaxf(m, __shfl_xor(m, 16));
            m = fmaxf(m, __shfl_xor(m, 32));
            const float m_new = fmaxf(m_run[s], m);
            const float alpha = fexp2(m_run[s] - m_new);
            m_run[s] = m_new;
            float psum = 0.f;
            #pragma unroll
            for (int ct = 0; ct < 4; ++ct)
                #pragma unroll
                for (int r = 0; r < 4; ++r) {
                    float e = fexp2(S[ct][r] - m_new);
                    S[ct][r] = e;
                    psum += e;
                }
            psum += __shfl_xor(psum, 16);
            psum += __shfl_xor(psum, 32);
            l_run[s] = l_run[s] * alpha + psum;

            // P^T -> wave-private slab (truncation pack), then B-frags
            #pragma unroll
            for (int ct = 0; ct < 4; ++ct) {
                uint2 pw = make_uint2(pack_hi(S[ct][0], S[ct][1]),
                                      pack_hi(S[ct][2], S[ct][3]));
                *(uint2*)&ps[lm * 68 + ct * 16 + quad * 4] = pw;
            }
            bf16x8 Pb0 = *(const bf16x8*)&ps[lm * 68 + quad * 8];
            bf16x8 Pb1 = *(const bf16x8*)&ps[lm * 68 + 32 + quad * 8];

            // O^T = O^T*alpha + V^T P^T
            #pragma unroll
            for (int nt = 0; nt < 4; ++nt) {
                f32x4 o = Oacc[s][nt];
                #pragma unroll
                for (int r = 0; r < 4; ++r) o[r] *= alpha;
                o = __builtin_amdgcn_mfma_f32_16x16x32_bf16(Vf[nt][0], Pb0, o, 0, 0, 0);
                o = __builtin_amdgcn_mfma_f32_16x16x32_bf16(Vf[nt][1], Pb1, o, 0, 0, 0);
                Oacc[s][nt] = o;
            }
        }

        __syncthreads();                        // one barrier per tile
        bb ^= 1;
    }

    // epilogue: O^T/l -> slab [q][d] -> coalesced stores (per strip)
    #pragma unroll
    for (int s = 0; s < 2; ++s) {
        const float inv_l = 1.f / l_run[s];
        #pragma unroll
        for (int nt = 0; nt < 4; ++nt) {
            ushort4 pk = make_ushort4(f2bf(Oacc[s][nt][0] * inv_l),
                                      f2bf(Oacc[s][nt][1] * inv_l),
                                      f2bf(Oacc[s][nt][2] * inv_l),
                                      f2bf(Oacc[s][nt][3] * inv_l));
            *(ushort4*)&ps[lm * 68 + nt * 16 + quad * 4] = pk;
        }
        #pragma unroll
        for (int cc = 0; cc < 2; ++cc) {
            int chunk = cc * 64 + L;
            int row = chunk >> 3, seg = chunk & 7;
            uint4 val = *(const uint4*)&ps[row * 68 + seg * 8];
            *(uint4*)&A[hb + (size_t)(q0 + w * 32 + s * 16 + row) * D_MODEL + seg * 8] = val;
        }
    }
}

// ---------------------------------------------------------------------------
extern "C" void kernel_launch(void* const* d_in, const int* in_sizes, int n_in,
                              void* d_out, int out_size, void* d_ws, size_t ws_size,
                              hipStream_t stream) {
    const float* q  = (const float*)d_in[0];
    const float* k  = (const float*)d_in[1];
    const float* v  = (const float*)d_in[2];
    const float* Wq = (const float*)d_in[4];
    const float* Wk = (const float*)d_in[5];
    const float* Wv = (const float*)d_in[6];
    const float* Wo = (const float*)d_in[7];
    float* out = (float*)d_out;

    char* ws = (char*)d_ws;
    const size_t MB = 1024 * 1024;
    unsigned short* qb  = (unsigned short*)(ws + 0 * MB);
    unsigned short* kb  = (unsigned short*)(ws + 8 * MB);
    unsigned short* vb  = (unsigned short*)(ws + 16 * MB);
    unsigned short* wqb = (unsigned short*)(ws + 24 * MB);
    unsigned short* wkb = (unsigned short*)(ws + 26 * MB);
    unsigned short* wvb = (unsigned short*)(ws + 28 * MB);
    unsigned short* wob = (unsigned short*)(ws + 30 * MB);
    unsigned short* Qp  = (unsigned short*)(ws + 32 * MB);
    unsigned short* Kp  = (unsigned short*)(ws + 40 * MB);
    unsigned short* VTp = (unsigned short*)(ws + 48 * MB);
    unsigned short* Ap  = (unsigned short*)(ws + 56 * MB);

    const int nX8 = BS * D_MODEL / 8;         // 524288
    const int nW8 = D_MODEL * D_MODEL / 8;    // 131072
    cast_all<<<dim3(nX8 / 256, 7), 256, 0, stream>>>(
        q, k, v, Wq, Wk, Wv, Wo, qb, kb, vb, wqb, wkb, wvb, wob, nX8, nW8);

    proj_gemm<<<dim3(D_MODEL / 128, BS / 128, 3), 256, 0, stream>>>(
        qb, kb, vb, wqb, wkb, wvb, Qp, Kp, VTp);

    attn_mfma<<<dim3(1024), 128, 0, stream>>>(Qp, Kp, VTp, Ap);

    out_gemm<<<dim3(D_MODEL / 64, BS / 128), 256, 0, stream>>>(Ap, wob, out);
}